// Round 1
// baseline (1493.612 us; speedup 1.0000x reference)
//
#include <hip/hip_runtime.h>

#define N_NODES 50000
#define N_EDGES 800000
#define IN_F 10
#define HID 256
#define EMB 128
#define BN_EPS 1e-5f

// ---------------- CSR build ----------------
__global__ void k_count(const int* __restrict__ dst, int* __restrict__ cnt) {
    int e = blockIdx.x * 256 + threadIdx.x;
    if (e < N_EDGES) atomicAdd(&cnt[dst[e]], 1);
}

__global__ void k_scan(const int* __restrict__ cnt, int* __restrict__ row_off,
                       int* __restrict__ fill_pos) {
    __shared__ int buf[1024];
    __shared__ int carry_s;
    int tid = threadIdx.x;
    if (tid == 0) carry_s = 0;
    __syncthreads();
    for (int base = 0; base < N_NODES; base += 1024) {
        int i = base + tid;
        int v = (i < N_NODES) ? cnt[i] : 0;
        buf[tid] = v;
        __syncthreads();
        for (int off = 1; off < 1024; off <<= 1) {
            int t = (tid >= off) ? buf[tid - off] : 0;
            __syncthreads();
            buf[tid] += t;
            __syncthreads();
        }
        int carry = carry_s;
        int excl = carry + buf[tid] - v;
        if (i < N_NODES) { row_off[i] = excl; fill_pos[i] = excl; }
        __syncthreads();
        if (tid == 0) carry_s = carry + buf[1023];
        __syncthreads();
    }
    if (tid == 0) row_off[N_NODES] = carry_s;
}

__global__ void k_scatter(const int* __restrict__ src, const int* __restrict__ dst,
                          int* __restrict__ fill_pos, int* __restrict__ sorted_src) {
    int e = blockIdx.x * 256 + threadIdx.x;
    if (e < N_EDGES) {
        int d = dst[e];
        int p = atomicAdd(&fill_pos[d], 1);
        sorted_src[p] = src[e];
    }
}

// ---------------- input projection ----------------
__global__ void k_input_proj(const float* __restrict__ x, const float* __restrict__ w,
                             const float* __restrict__ bias, float* __restrict__ h) {
    int i = blockIdx.x;
    int j = threadIdx.x;
    float acc = bias[j];
#pragma unroll
    for (int k = 0; k < IN_F; k++) acc += x[i * IN_F + k] * w[k * HID + j];
    h[i * HID + j] = acc;
}

// ---------------- batchnorm ----------------
__global__ void k_bn_stats(const float* __restrict__ h, float* __restrict__ stats) {
    int j = threadIdx.x;  // 256 = HID
    float s = 0.f, sq = 0.f;
    for (int i = blockIdx.x; i < N_NODES; i += gridDim.x) {
        float v = h[i * HID + j];
        s += v; sq += v * v;
    }
    atomicAdd(&stats[j], s);
    atomicAdd(&stats[HID + j], sq);
}

__global__ void k_bn_apply_relu(float* __restrict__ h, const float* __restrict__ stats,
                                const float* __restrict__ g, const float* __restrict__ b) {
    int idx = blockIdx.x * 256 + threadIdx.x;
    if (idx >= N_NODES * HID) return;
    int j = idx & (HID - 1);
    const float invn = 1.0f / (float)N_NODES;
    float mu = stats[j] * invn;
    float var = stats[HID + j] * invn - mu * mu;
    float v = (h[idx] - mu) * rsqrtf(var + BN_EPS) * g[j] + b[j];
    h[idx] = v > 0.f ? v : 0.f;
}

// ---------------- neighbor mean aggregation (one wave per node) ----------------
__global__ void k_aggregate(const float* __restrict__ h, const int* __restrict__ row_off,
                            const int* __restrict__ sorted_src, float* __restrict__ agg) {
    int w = (blockIdx.x * blockDim.x + threadIdx.x) >> 6;
    int lane = threadIdx.x & 63;
    if (w >= N_NODES) return;
    int beg = row_off[w], end = row_off[w + 1];
    float4 acc = {0.f, 0.f, 0.f, 0.f};
    const float4* h4 = (const float4*)h;  // HID=256 -> 64 float4 per row, one per lane
    for (int e = beg; e < end; e++) {
        int s = sorted_src[e];
        float4 v = h4[(size_t)s * 64 + lane];
        acc.x += v.x; acc.y += v.y; acc.z += v.z; acc.w += v.w;
    }
    int d = end - beg;
    float inv = 1.0f / (float)(d > 1 ? d : 1);
    float4 o = {acc.x * inv, acc.y * inv, acc.z * inv, acc.w * inv};
    ((float4*)agg)[(size_t)w * 64 + lane] = o;
}

// ---------------- fused dual GEMM: C = A1@B1 + A2@B2 + bias ----------------
// A [N_NODES, 256] row-major, B [256, nout] row-major. 128x128 tile, 256 thr, 8x8/thread.
__global__ __launch_bounds__(256) void k_gemm(
        const float* __restrict__ A1, const float* __restrict__ B1,
        const float* __restrict__ A2, const float* __restrict__ B2,
        const float* __restrict__ bias, float* __restrict__ C, int nout) {
    __shared__ float As[16][132];
    __shared__ float Bs[16][132];
    int tx = threadIdx.x & 15, ty = threadIdx.x >> 4;
    int r0 = blockIdx.y * 128, c0 = blockIdx.x * 128;
    float acc[8][8] = {};

    for (int s = 0; s < 2; s++) {
        const float* A = s ? A2 : A1;
        const float* B = s ? B2 : B1;
        for (int k0 = 0; k0 < HID; k0 += 16) {
            // A tile: 128 rows x 16 k, transposed into As[k][row]
            {
                int kk = threadIdx.x & 15;
                int rbase = threadIdx.x >> 4;
#pragma unroll
                for (int p = 0; p < 8; p++) {
                    int row = p * 16 + rbase;
                    int r = r0 + row;
                    As[kk][row] = (r < N_NODES) ? A[(size_t)r * HID + k0 + kk] : 0.f;
                }
            }
            // B tile: 16 k x 128 cols
            {
#pragma unroll
                for (int p = 0; p < 8; p++) {
                    int idx = p * 256 + threadIdx.x;
                    int k = idx >> 7, col = idx & 127;
                    Bs[k][col] = B[(size_t)(k0 + k) * nout + c0 + col];
                }
            }
            __syncthreads();
#pragma unroll
            for (int k = 0; k < 16; k++) {
                float a[8], b[8];
                *(float4*)&a[0] = *(const float4*)&As[k][ty * 8];
                *(float4*)&a[4] = *(const float4*)&As[k][ty * 8 + 4];
                *(float4*)&b[0] = *(const float4*)&Bs[k][tx * 8];
                *(float4*)&b[4] = *(const float4*)&Bs[k][tx * 8 + 4];
#pragma unroll
                for (int i = 0; i < 8; i++)
#pragma unroll
                    for (int j = 0; j < 8; j++) acc[i][j] += a[i] * b[j];
            }
            __syncthreads();
        }
    }
#pragma unroll
    for (int i = 0; i < 8; i++) {
        int r = r0 + ty * 8 + i;
        if (r >= N_NODES) continue;
#pragma unroll
        for (int j = 0; j < 8; j++) {
            int c = c0 + tx * 8 + j;
            C[(size_t)r * nout + c] = acc[i][j] + bias[c];
        }
    }
}

extern "C" void kernel_launch(void* const* d_in, const int* in_sizes, int n_in,
                              void* d_out, int out_size, void* d_ws, size_t ws_size,
                              hipStream_t stream) {
    const float* x    = (const float*)d_in[0];
    const int*   ei   = (const int*)d_in[1];   // [2, E]: src row then dst row
    const float* w_in = (const float*)d_in[2];
    const float* b_in = (const float*)d_in[3];
    const float* g_in = (const float*)d_in[4];
    const float* be_in= (const float*)d_in[5];
    const float* wl1  = (const float*)d_in[6];
    const float* bl1  = (const float*)d_in[7];
    const float* wr1  = (const float*)d_in[8];
    const float* g1   = (const float*)d_in[9];
    const float* be1  = (const float*)d_in[10];
    const float* wl2  = (const float*)d_in[11];
    const float* bl2  = (const float*)d_in[12];
    const float* wr2  = (const float*)d_in[13];
    const float* g2   = (const float*)d_in[14];
    const float* be2  = (const float*)d_in[15];
    const float* wl3  = (const float*)d_in[16];
    const float* bl3  = (const float*)d_in[17];
    const float* wr3  = (const float*)d_in[18];
    float* out = (float*)d_out;

    char* p = (char*)d_ws;
    auto alloc = [&](size_t bytes) -> void* {
        void* r = (void*)p;
        p += (bytes + 255) & ~(size_t)255;
        return r;
    };
    float* bufA       = (float*)alloc((size_t)N_NODES * HID * 4);
    float* bufB       = (float*)alloc((size_t)N_NODES * HID * 4);
    float* agg        = (float*)alloc((size_t)N_NODES * HID * 4);
    int*   cnt        = (int*)alloc((size_t)N_NODES * 4);
    int*   row_off    = (int*)alloc((size_t)(N_NODES + 1) * 4);
    int*   fill_pos   = (int*)alloc((size_t)N_NODES * 4);
    int*   sorted_src = (int*)alloc((size_t)N_EDGES * 4);
    float* stats      = (float*)alloc((size_t)2 * HID * 4);

    const int* e_src = ei;
    const int* e_dst = ei + N_EDGES;

    // CSR build (counting sort by dst)
    hipMemsetAsync(cnt, 0, (size_t)N_NODES * 4, stream);
    k_count<<<(N_EDGES + 255) / 256, 256, 0, stream>>>(e_dst, cnt);
    k_scan<<<1, 1024, 0, stream>>>(cnt, row_off, fill_pos);
    k_scatter<<<(N_EDGES + 255) / 256, 256, 0, stream>>>(e_src, e_dst, fill_pos, sorted_src);

    auto bn = [&](float* h, const float* g, const float* b) {
        hipMemsetAsync(stats, 0, 2 * HID * 4, stream);
        k_bn_stats<<<1024, 256, 0, stream>>>(h, stats);
        k_bn_apply_relu<<<(N_NODES * HID + 255) / 256, 256, 0, stream>>>(h, stats, g, b);
    };

    // input projection + BN + ReLU
    k_input_proj<<<N_NODES, 256, 0, stream>>>(x, w_in, b_in, bufA);
    bn(bufA, g_in, be_in);

    dim3 gemm_block(256);
    dim3 gemm_grid2(HID / 128, (N_NODES + 127) / 128);
    dim3 gemm_grid1(EMB / 128, (N_NODES + 127) / 128);
    int agg_blocks = (N_NODES + 3) / 4;  // 4 waves per 256-thread block, 1 wave/node

    // SAGE layer 1
    k_aggregate<<<agg_blocks, 256, 0, stream>>>(bufA, row_off, sorted_src, agg);
    k_gemm<<<gemm_grid2, gemm_block, 0, stream>>>(agg, wl1, bufA, wr1, bl1, bufB, HID);
    bn(bufB, g1, be1);

    // SAGE layer 2
    k_aggregate<<<agg_blocks, 256, 0, stream>>>(bufB, row_off, sorted_src, agg);
    k_gemm<<<gemm_grid2, gemm_block, 0, stream>>>(agg, wl2, bufB, wr2, bl2, bufA, HID);
    bn(bufA, g2, be2);

    // SAGE layer 3 (no BN/ReLU) -> d_out
    k_aggregate<<<agg_blocks, 256, 0, stream>>>(bufA, row_off, sorted_src, agg);
    k_gemm<<<gemm_grid1, gemm_block, 0, stream>>>(agg, wl3, bufA, wr3, bl3, out, EMB);
}

// Round 2
// 915.700 us; speedup vs baseline: 1.6311x; 1.6311x over previous
//
#include <hip/hip_runtime.h>

#define N_NODES 50000
#define N_EDGES 800000
#define IN_F 10
#define HID 256
#define EMB 128
#define BN_EPS 1e-5f

typedef __attribute__((ext_vector_type(8))) short short8;
typedef __attribute__((ext_vector_type(4))) float floatx4;

__device__ __forceinline__ unsigned short f2bf(float f) {
    unsigned u = __float_as_uint(f);
    unsigned r = (u + 0x7fffu + ((u >> 16) & 1u)) >> 16;
    return (unsigned short)r;
}
__device__ __forceinline__ float bf_lo(unsigned int u) { return __uint_as_float(u << 16); }
__device__ __forceinline__ float bf_hi(unsigned int u) { return __uint_as_float(u & 0xffff0000u); }

// ---------------- CSR build ----------------
__global__ void k_count(const int* __restrict__ dst, int* __restrict__ cnt) {
    int e = blockIdx.x * 256 + threadIdx.x;
    if (e < N_EDGES) atomicAdd(&cnt[dst[e]], 1);
}

__global__ void k_scan(const int* __restrict__ cnt, int* __restrict__ row_off,
                       int* __restrict__ fill_pos) {
    __shared__ int buf[1024];
    __shared__ int carry_s;
    int tid = threadIdx.x;
    if (tid == 0) carry_s = 0;
    __syncthreads();
    for (int base = 0; base < N_NODES; base += 1024) {
        int i = base + tid;
        int v = (i < N_NODES) ? cnt[i] : 0;
        buf[tid] = v;
        __syncthreads();
        for (int off = 1; off < 1024; off <<= 1) {
            int t = (tid >= off) ? buf[tid - off] : 0;
            __syncthreads();
            buf[tid] += t;
            __syncthreads();
        }
        int carry = carry_s;
        int excl = carry + buf[tid] - v;
        if (i < N_NODES) { row_off[i] = excl; fill_pos[i] = excl; }
        __syncthreads();
        if (tid == 0) carry_s = carry + buf[1023];
        __syncthreads();
    }
    if (tid == 0) row_off[N_NODES] = carry_s;
}

__global__ void k_scatter(const int* __restrict__ src, const int* __restrict__ dst,
                          int* __restrict__ fill_pos, int* __restrict__ sorted_src) {
    int e = blockIdx.x * 256 + threadIdx.x;
    if (e < N_EDGES) {
        int d = dst[e];
        int p = atomicAdd(&fill_pos[d], 1);
        sorted_src[p] = src[e];
    }
}

// ---------------- weight convert + transpose: W[k][n] fp32 -> Wt[n][k] bf16 (K=256) --------
__global__ void k_wconv(const float* __restrict__ w, unsigned short* __restrict__ wt, int N) {
    int idx = blockIdx.x * 256 + threadIdx.x;  // over N*256
    int n = idx >> 8, k = idx & 255;
    if (n < N) wt[idx] = f2bf(w[k * N + n]);
}

// ---------------- input projection -> bf16 h ----------------
__global__ void k_input_proj(const float* __restrict__ x, const float* __restrict__ w,
                             const float* __restrict__ bias, unsigned short* __restrict__ h) {
    int i = blockIdx.x;
    int j = threadIdx.x;
    float acc = bias[j];
#pragma unroll
    for (int k = 0; k < IN_F; k++) acc += x[i * IN_F + k] * w[k * HID + j];
    h[(size_t)i * HID + j] = f2bf(acc);
}

// ---------------- batchnorm on bf16 buffers ----------------
__global__ void k_bn_stats(const unsigned short* __restrict__ h, float* __restrict__ stats) {
    int jp = threadIdx.x;  // 0..127, handles cols 2jp, 2jp+1
    const unsigned int* h32 = (const unsigned int*)h;
    float s0 = 0.f, s1 = 0.f, q0 = 0.f, q1 = 0.f;
    for (int i = blockIdx.x; i < N_NODES; i += gridDim.x) {
        unsigned int v = h32[(size_t)i * 128 + jp];
        float f0 = bf_lo(v), f1 = bf_hi(v);
        s0 += f0; q0 += f0 * f0;
        s1 += f1; q1 += f1 * f1;
    }
    int j0 = 2 * jp;
    atomicAdd(&stats[j0], s0);
    atomicAdd(&stats[j0 + 1], s1);
    atomicAdd(&stats[HID + j0], q0);
    atomicAdd(&stats[HID + j0 + 1], q1);
}

__global__ void k_bn_finalize(const float* __restrict__ stats, const float* __restrict__ g,
                              const float* __restrict__ b, float* __restrict__ ss) {
    int j = threadIdx.x;  // 256
    const float invn = 1.0f / (float)N_NODES;
    float mu = stats[j] * invn;
    float var = stats[HID + j] * invn - mu * mu;
    float sc = g[j] * rsqrtf(var + BN_EPS);
    ss[j] = sc;              // scale
    ss[HID + j] = b[j] - mu * sc;  // shift
}

__global__ void k_bn_apply_relu(unsigned short* __restrict__ h, const float* __restrict__ ss) {
    int idx = blockIdx.x * 256 + threadIdx.x;  // pair index over N_NODES*128
    if (idx >= N_NODES * 128) return;
    int jp = idx & 127;
    int j0 = 2 * jp;
    unsigned int v = ((unsigned int*)h)[idx];
    float f0 = bf_lo(v) * ss[j0] + ss[HID + j0];
    float f1 = bf_hi(v) * ss[j0 + 1] + ss[HID + j0 + 1];
    f0 = f0 > 0.f ? f0 : 0.f;
    f1 = f1 > 0.f ? f1 : 0.f;
    ((unsigned int*)h)[idx] = (unsigned int)f2bf(f0) | ((unsigned int)f2bf(f1) << 16);
}

// ---------------- neighbor mean aggregation (one wave per node, bf16) ----------------
__global__ void k_aggregate(const unsigned short* __restrict__ h, const int* __restrict__ row_off,
                            const int* __restrict__ sorted_src, unsigned short* __restrict__ agg) {
    int w = (blockIdx.x * blockDim.x + threadIdx.x) >> 6;
    int lane = threadIdx.x & 63;
    if (w >= N_NODES) return;
    int beg = row_off[w], end = row_off[w + 1];
    const uint2* h2 = (const uint2*)h;  // 256 bf16 per row = 64 uint2, one per lane
    float a0 = 0.f, a1 = 0.f, a2 = 0.f, a3 = 0.f;
    for (int e = beg; e < end; e++) {
        int s = sorted_src[e];
        uint2 v = h2[(size_t)s * 64 + lane];
        a0 += bf_lo(v.x); a1 += bf_hi(v.x);
        a2 += bf_lo(v.y); a3 += bf_hi(v.y);
    }
    int d = end - beg;
    float inv = 1.0f / (float)(d > 1 ? d : 1);
    a0 *= inv; a1 *= inv; a2 *= inv; a3 *= inv;
    uint2 o;
    o.x = (unsigned int)f2bf(a0) | ((unsigned int)f2bf(a1) << 16);
    o.y = (unsigned int)f2bf(a2) | ((unsigned int)f2bf(a3) << 16);
    ((uint2*)agg)[(size_t)w * 64 + lane] = o;
}

// ---------------- dual bf16 MFMA GEMM: C = A1@B1t^T + A2@B2t^T + bias ----------------
// A: [M,256] bf16 row-major. Bt: [N,256] bf16 row-major (pre-transposed weight).
// 128x128 tile, 4 waves (2x2), each wave 64x64 = 4x4 tiles of 16x16x32 MFMA.
#define BK 64
#define LPAD 72  // LDS row stride in bf16 elements (144 B, 16B-aligned, breaks pow2)

template <int NCOL, bool F32OUT>
__global__ __launch_bounds__(256) void k_gemm_mfma(
        const unsigned short* __restrict__ A1, const unsigned short* __restrict__ B1t,
        const unsigned short* __restrict__ A2, const unsigned short* __restrict__ B2t,
        const float* __restrict__ bias, void* __restrict__ Cout) {
    __shared__ unsigned short As[128 * LPAD];
    __shared__ unsigned short Bs[128 * LPAD];
    int t = threadIdx.x;
    int wave = t >> 6, lane = t & 63;
    int wm = wave >> 1, wn = wave & 1;
    int quad = lane >> 4, l15 = lane & 15;
    int r0 = blockIdx.y * 128, c0 = blockIdx.x * 128;

    floatx4 acc[4][4];
#pragma unroll
    for (int i = 0; i < 4; i++)
#pragma unroll
        for (int j = 0; j < 4; j++) acc[i][j] = (floatx4){0.f, 0.f, 0.f, 0.f};

    int lrow = t >> 3;  // 0..31
    int lseg = t & 7;   // 0..7 (16B segments of a 64-elem k-slice)

#pragma unroll
    for (int s = 0; s < 2; s++) {
        const unsigned short* A = s ? A2 : A1;
        const unsigned short* B = s ? B2t : B1t;
        for (int k0 = 0; k0 < HID; k0 += BK) {
            // stage A tile (128 rows x 64 k) and Bt tile (128 n-rows x 64 k)
#pragma unroll
            for (int it = 0; it < 4; it++) {
                int row = lrow + it * 32;
                int r = r0 + row;
                uint4 va;
                if (r < N_NODES) va = *(const uint4*)&A[(size_t)r * HID + k0 + lseg * 8];
                else va = (uint4){0u, 0u, 0u, 0u};
                *(uint4*)&As[row * LPAD + lseg * 8] = va;
                uint4 vb = *(const uint4*)&B[(size_t)(c0 + row) * HID + k0 + lseg * 8];
                *(uint4*)&Bs[row * LPAD + lseg * 8] = vb;
            }
            __syncthreads();
#pragma unroll
            for (int kc = 0; kc < 2; kc++) {
                short8 a[4], b[4];
#pragma unroll
                for (int i = 0; i < 4; i++)
                    a[i] = *(const short8*)&As[(wm * 64 + i * 16 + l15) * LPAD + kc * 32 + quad * 8];
#pragma unroll
                for (int j = 0; j < 4; j++)
                    b[j] = *(const short8*)&Bs[(wn * 64 + j * 16 + l15) * LPAD + kc * 32 + quad * 8];
#pragma unroll
                for (int i = 0; i < 4; i++)
#pragma unroll
                    for (int j = 0; j < 4; j++)
                        acc[i][j] = __builtin_amdgcn_mfma_f32_16x16x32_bf16(a[i], b[j], acc[i][j], 0, 0, 0);
            }
            __syncthreads();
        }
    }

    // epilogue: C[m][n] with col=lane&15, row=quad*4+reg (m89-verified layout)
    float bv[4];
#pragma unroll
    for (int j = 0; j < 4; j++) bv[j] = bias[c0 + wn * 64 + j * 16 + l15];

#pragma unroll
    for (int i = 0; i < 4; i++) {
#pragma unroll
        for (int r = 0; r < 4; r++) {
            int m = r0 + wm * 64 + i * 16 + quad * 4 + r;
            if (m >= N_NODES) continue;
#pragma unroll
            for (int j = 0; j < 4; j++) {
                int n = c0 + wn * 64 + j * 16 + l15;
                float v = acc[i][j][r] + bv[j];
                if (F32OUT) ((float*)Cout)[(size_t)m * NCOL + n] = v;
                else ((unsigned short*)Cout)[(size_t)m * NCOL + n] = f2bf(v);
            }
        }
    }
}

extern "C" void kernel_launch(void* const* d_in, const int* in_sizes, int n_in,
                              void* d_out, int out_size, void* d_ws, size_t ws_size,
                              hipStream_t stream) {
    const float* x    = (const float*)d_in[0];
    const int*   ei   = (const int*)d_in[1];
    const float* w_in = (const float*)d_in[2];
    const float* b_in = (const float*)d_in[3];
    const float* g_in = (const float*)d_in[4];
    const float* be_in= (const float*)d_in[5];
    const float* wl1  = (const float*)d_in[6];
    const float* bl1  = (const float*)d_in[7];
    const float* wr1  = (const float*)d_in[8];
    const float* g1   = (const float*)d_in[9];
    const float* be1  = (const float*)d_in[10];
    const float* wl2  = (const float*)d_in[11];
    const float* bl2  = (const float*)d_in[12];
    const float* wr2  = (const float*)d_in[13];
    const float* g2   = (const float*)d_in[14];
    const float* be2  = (const float*)d_in[15];
    const float* wl3  = (const float*)d_in[16];
    const float* bl3  = (const float*)d_in[17];
    const float* wr3  = (const float*)d_in[18];
    float* out = (float*)d_out;

    char* p = (char*)d_ws;
    auto alloc = [&](size_t bytes) -> void* {
        void* r = (void*)p;
        p += (bytes + 255) & ~(size_t)255;
        return r;
    };
    unsigned short* bufA = (unsigned short*)alloc((size_t)N_NODES * HID * 2);
    unsigned short* bufB = (unsigned short*)alloc((size_t)N_NODES * HID * 2);
    unsigned short* agg  = (unsigned short*)alloc((size_t)N_NODES * HID * 2);
    unsigned short* wl1t = (unsigned short*)alloc((size_t)HID * HID * 2);
    unsigned short* wr1t = (unsigned short*)alloc((size_t)HID * HID * 2);
    unsigned short* wl2t = (unsigned short*)alloc((size_t)HID * HID * 2);
    unsigned short* wr2t = (unsigned short*)alloc((size_t)HID * HID * 2);
    unsigned short* wl3t = (unsigned short*)alloc((size_t)EMB * HID * 2);
    unsigned short* wr3t = (unsigned short*)alloc((size_t)EMB * HID * 2);
    int*   cnt        = (int*)alloc((size_t)N_NODES * 4);
    int*   row_off    = (int*)alloc((size_t)(N_NODES + 1) * 4);
    int*   fill_pos   = (int*)alloc((size_t)N_NODES * 4);
    int*   sorted_src = (int*)alloc((size_t)N_EDGES * 4);
    float* stats      = (float*)alloc((size_t)2 * HID * 4);
    float* ss         = (float*)alloc((size_t)2 * HID * 4);

    const int* e_src = ei;
    const int* e_dst = ei + N_EDGES;

    // CSR build (counting sort by dst)
    hipMemsetAsync(cnt, 0, (size_t)N_NODES * 4, stream);
    k_count<<<(N_EDGES + 255) / 256, 256, 0, stream>>>(e_dst, cnt);
    k_scan<<<1, 1024, 0, stream>>>(cnt, row_off, fill_pos);
    k_scatter<<<(N_EDGES + 255) / 256, 256, 0, stream>>>(e_src, e_dst, fill_pos, sorted_src);

    // weights -> bf16 transposed
    k_wconv<<<HID, 256, 0, stream>>>(wl1, wl1t, HID);
    k_wconv<<<HID, 256, 0, stream>>>(wr1, wr1t, HID);
    k_wconv<<<HID, 256, 0, stream>>>(wl2, wl2t, HID);
    k_wconv<<<HID, 256, 0, stream>>>(wr2, wr2t, HID);
    k_wconv<<<EMB, 256, 0, stream>>>(wl3, wl3t, EMB);
    k_wconv<<<EMB, 256, 0, stream>>>(wr3, wr3t, EMB);

    auto bn = [&](unsigned short* h, const float* g, const float* b) {
        hipMemsetAsync(stats, 0, 2 * HID * 4, stream);
        k_bn_stats<<<1024, 128, 0, stream>>>(h, stats);
        k_bn_finalize<<<1, 256, 0, stream>>>(stats, g, b, ss);
        k_bn_apply_relu<<<(N_NODES * 128 + 255) / 256, 256, 0, stream>>>(h, ss);
    };

    // input projection + BN + ReLU
    k_input_proj<<<N_NODES, 256, 0, stream>>>(x, w_in, b_in, bufA);
    bn(bufA, g_in, be_in);

    dim3 gblock(256);
    dim3 grid2(2, (N_NODES + 127) / 128);  // N=256
    dim3 grid1(1, (N_NODES + 127) / 128);  // N=128
    int agg_blocks = (N_NODES + 3) / 4;

    // SAGE layer 1
    k_aggregate<<<agg_blocks, 256, 0, stream>>>(bufA, row_off, sorted_src, agg);
    k_gemm_mfma<HID, false><<<grid2, gblock, 0, stream>>>(agg, wl1t, bufA, wr1t, bl1, bufB);
    bn(bufB, g1, be1);

    // SAGE layer 2
    k_aggregate<<<agg_blocks, 256, 0, stream>>>(bufB, row_off, sorted_src, agg);
    k_gemm_mfma<HID, false><<<grid2, gblock, 0, stream>>>(agg, wl2t, bufB, wr2t, bl2, bufA);
    bn(bufA, g2, be2);

    // SAGE layer 3 (no BN/ReLU) -> fp32 d_out
    k_aggregate<<<agg_blocks, 256, 0, stream>>>(bufA, row_off, sorted_src, agg);
    k_gemm_mfma<EMB, true><<<grid1, gblock, 0, stream>>>(agg, wl3t, bufA, wr3t, bl3, out);
}

// Round 3
// 751.318 us; speedup vs baseline: 1.9880x; 1.2188x over previous
//
#include <hip/hip_runtime.h>

#define N_NODES 50000
#define N_EDGES 800000
#define IN_F 10
#define HID 256
#define EMB 128
#define BN_EPS 1e-5f
#define N_SCAN_BLKS ((N_NODES + 255) / 256)  // 196

typedef __attribute__((ext_vector_type(8))) short short8;
typedef __attribute__((ext_vector_type(4))) float floatx4;

__device__ __forceinline__ unsigned short f2bf(float f) {
    unsigned u = __float_as_uint(f);
    unsigned r = (u + 0x7fffu + ((u >> 16) & 1u)) >> 16;
    return (unsigned short)r;
}
__device__ __forceinline__ float bf_lo(unsigned int u) { return __uint_as_float(u << 16); }
__device__ __forceinline__ float bf_hi(unsigned int u) { return __uint_as_float(u & 0xffff0000u); }

// ---------------- CSR build ----------------
__global__ void k_count(const int* __restrict__ dst, int* __restrict__ cnt) {
    int e = blockIdx.x * 256 + threadIdx.x;
    if (e < N_EDGES) atomicAdd(&cnt[dst[e]], 1);
}

// phase 1: per-block sums
__global__ void k_reduce_cnt(const int* __restrict__ cnt, int* __restrict__ part) {
    __shared__ int sdata[256];
    int i = blockIdx.x * 256 + threadIdx.x;
    sdata[threadIdx.x] = (i < N_NODES) ? cnt[i] : 0;
    __syncthreads();
    for (int off = 128; off > 0; off >>= 1) {
        if (threadIdx.x < off) sdata[threadIdx.x] += sdata[threadIdx.x + off];
        __syncthreads();
    }
    if (threadIdx.x == 0) part[blockIdx.x] = sdata[0];
}

// phase 2: scan the partials (196 <= 256), write exclusive offsets + grand total
__global__ void k_scan_part(const int* __restrict__ part, int* __restrict__ partoff,
                            int* __restrict__ row_off_last) {
    __shared__ int buf[256];
    int tid = threadIdx.x;
    int v = (tid < N_SCAN_BLKS) ? part[tid] : 0;
    buf[tid] = v;
    __syncthreads();
    for (int off = 1; off < 256; off <<= 1) {
        int t = (tid >= off) ? buf[tid - off] : 0;
        __syncthreads();
        buf[tid] += t;
        __syncthreads();
    }
    if (tid < N_SCAN_BLKS) partoff[tid] = buf[tid] - v;
    if (tid == 255) *row_off_last = buf[255];
}

// phase 3: local exclusive scan + block offset
__global__ void k_scan_final(const int* __restrict__ cnt, const int* __restrict__ partoff,
                             int* __restrict__ row_off, int* __restrict__ fill_pos) {
    __shared__ int buf[256];
    int tid = threadIdx.x;
    int i = blockIdx.x * 256 + tid;
    int v = (i < N_NODES) ? cnt[i] : 0;
    buf[tid] = v;
    __syncthreads();
    for (int off = 1; off < 256; off <<= 1) {
        int t = (tid >= off) ? buf[tid - off] : 0;
        __syncthreads();
        buf[tid] += t;
        __syncthreads();
    }
    if (i < N_NODES) {
        int excl = partoff[blockIdx.x] + buf[tid] - v;
        row_off[i] = excl;
        fill_pos[i] = excl;
    }
}

__global__ void k_scatter(const int* __restrict__ src, const int* __restrict__ dst,
                          int* __restrict__ fill_pos, int* __restrict__ sorted_src) {
    int e = blockIdx.x * 256 + threadIdx.x;
    if (e < N_EDGES) {
        int d = dst[e];
        int p = atomicAdd(&fill_pos[d], 1);
        sorted_src[p] = src[e];
    }
}

// ---------------- weight convert + transpose: W[k][n] fp32 -> Wt[n][k] bf16 (K=256) --------
__global__ void k_wconv(const float* __restrict__ w, unsigned short* __restrict__ wt, int N) {
    int idx = blockIdx.x * 256 + threadIdx.x;  // over N*256
    int n = idx >> 8, k = idx & 255;
    if (n < N) wt[idx] = f2bf(w[k * N + n]);
}

// ---------------- input projection -> bf16 h ----------------
__global__ void k_input_proj(const float* __restrict__ x, const float* __restrict__ w,
                             const float* __restrict__ bias, unsigned short* __restrict__ h) {
    int i = blockIdx.x;
    int j = threadIdx.x;
    float acc = bias[j];
#pragma unroll
    for (int k = 0; k < IN_F; k++) acc += x[i * IN_F + k] * w[k * HID + j];
    h[(size_t)i * HID + j] = f2bf(acc);
}

// ---------------- batchnorm on bf16 buffers ----------------
__global__ void k_bn_stats(const unsigned short* __restrict__ h, float* __restrict__ stats) {
    int jp = threadIdx.x;  // 0..127, handles cols 2jp, 2jp+1
    const unsigned int* h32 = (const unsigned int*)h;
    float s0 = 0.f, s1 = 0.f, q0 = 0.f, q1 = 0.f;
    for (int i = blockIdx.x; i < N_NODES; i += gridDim.x) {
        unsigned int v = h32[(size_t)i * 128 + jp];
        float f0 = bf_lo(v), f1 = bf_hi(v);
        s0 += f0; q0 += f0 * f0;
        s1 += f1; q1 += f1 * f1;
    }
    int j0 = 2 * jp;
    atomicAdd(&stats[j0], s0);
    atomicAdd(&stats[j0 + 1], s1);
    atomicAdd(&stats[HID + j0], q0);
    atomicAdd(&stats[HID + j0 + 1], q1);
}

__global__ void k_bn_finalize(const float* __restrict__ stats, const float* __restrict__ g,
                              const float* __restrict__ b, float* __restrict__ ss) {
    int j = threadIdx.x;  // 256
    const float invn = 1.0f / (float)N_NODES;
    float mu = stats[j] * invn;
    float var = stats[HID + j] * invn - mu * mu;
    float sc = g[j] * rsqrtf(var + BN_EPS);
    ss[j] = sc;                    // scale
    ss[HID + j] = b[j] - mu * sc;  // shift
}

__global__ void k_bn_apply_relu(unsigned short* __restrict__ h, const float* __restrict__ ss) {
    int idx = blockIdx.x * 256 + threadIdx.x;  // uint4 index over N_NODES*32
    if (idx >= N_NODES * 32) return;
    int q = idx & 31;
    int j0 = q * 8;
    uint4 v = ((uint4*)h)[idx];
    const float4* sc4 = (const float4*)ss;
    const float4* sh4 = (const float4*)(ss + HID);
    float4 sa = sc4[j0 / 4], sb = sc4[j0 / 4 + 1];
    float4 ha = sh4[j0 / 4], hb = sh4[j0 / 4 + 1];
    float f0 = bf_lo(v.x) * sa.x + ha.x;
    float f1 = bf_hi(v.x) * sa.y + ha.y;
    float f2 = bf_lo(v.y) * sa.z + ha.z;
    float f3 = bf_hi(v.y) * sa.w + ha.w;
    float f4 = bf_lo(v.z) * sb.x + hb.x;
    float f5 = bf_hi(v.z) * sb.y + hb.y;
    float f6 = bf_lo(v.w) * sb.z + hb.z;
    float f7 = bf_hi(v.w) * sb.w + hb.w;
    f0 = fmaxf(f0, 0.f); f1 = fmaxf(f1, 0.f); f2 = fmaxf(f2, 0.f); f3 = fmaxf(f3, 0.f);
    f4 = fmaxf(f4, 0.f); f5 = fmaxf(f5, 0.f); f6 = fmaxf(f6, 0.f); f7 = fmaxf(f7, 0.f);
    uint4 o;
    o.x = (unsigned)f2bf(f0) | ((unsigned)f2bf(f1) << 16);
    o.y = (unsigned)f2bf(f2) | ((unsigned)f2bf(f3) << 16);
    o.z = (unsigned)f2bf(f4) | ((unsigned)f2bf(f5) << 16);
    o.w = (unsigned)f2bf(f6) | ((unsigned)f2bf(f7) << 16);
    ((uint4*)h)[idx] = o;
}

// ---------------- neighbor mean aggregation: 2 nodes/wave, 32 lanes x uint4 each ---------
__global__ void k_aggregate(const unsigned short* __restrict__ h, const int* __restrict__ row_off,
                            const int* __restrict__ sorted_src, unsigned short* __restrict__ agg) {
    int node = (blockIdx.x * blockDim.x + threadIdx.x) >> 5;  // half-wave per node
    int lane = threadIdx.x & 31;
    if (node >= N_NODES) return;
    int beg = row_off[node], end = row_off[node + 1];
    const uint4* h4 = (const uint4*)h;  // 256 bf16 per row = 32 uint4
    float a0 = 0.f, a1 = 0.f, a2 = 0.f, a3 = 0.f, a4 = 0.f, a5 = 0.f, a6 = 0.f, a7 = 0.f;
    for (int e = beg; e < end; e++) {
        int s = sorted_src[e];
        uint4 v = h4[(size_t)s * 32 + lane];
        a0 += bf_lo(v.x); a1 += bf_hi(v.x);
        a2 += bf_lo(v.y); a3 += bf_hi(v.y);
        a4 += bf_lo(v.z); a5 += bf_hi(v.z);
        a6 += bf_lo(v.w); a7 += bf_hi(v.w);
    }
    int d = end - beg;
    float inv = 1.0f / (float)(d > 1 ? d : 1);
    uint4 o;
    o.x = (unsigned)f2bf(a0 * inv) | ((unsigned)f2bf(a1 * inv) << 16);
    o.y = (unsigned)f2bf(a2 * inv) | ((unsigned)f2bf(a3 * inv) << 16);
    o.z = (unsigned)f2bf(a4 * inv) | ((unsigned)f2bf(a5 * inv) << 16);
    o.w = (unsigned)f2bf(a6 * inv) | ((unsigned)f2bf(a7 * inv) << 16);
    ((uint4*)agg)[(size_t)node * 32 + lane] = o;
}

// ---------------- dual bf16 MFMA GEMM: C = A1@B1t^T + A2@B2t^T + bias ----------------
#define BK 64
#define LPAD 72

template <int NCOL, bool F32OUT>
__global__ __launch_bounds__(256) void k_gemm_mfma(
        const unsigned short* __restrict__ A1, const unsigned short* __restrict__ B1t,
        const unsigned short* __restrict__ A2, const unsigned short* __restrict__ B2t,
        const float* __restrict__ bias, void* __restrict__ Cout) {
    __shared__ unsigned short As[128 * LPAD];
    __shared__ unsigned short Bs[128 * LPAD];
    int t = threadIdx.x;
    int wave = t >> 6, lane = t & 63;
    int wm = wave >> 1, wn = wave & 1;
    int quad = lane >> 4, l15 = lane & 15;
    int r0 = blockIdx.y * 128, c0 = blockIdx.x * 128;

    floatx4 acc[4][4];
#pragma unroll
    for (int i = 0; i < 4; i++)
#pragma unroll
        for (int j = 0; j < 4; j++) acc[i][j] = (floatx4){0.f, 0.f, 0.f, 0.f};

    int lrow = t >> 3;
    int lseg = t & 7;

#pragma unroll
    for (int s = 0; s < 2; s++) {
        const unsigned short* A = s ? A2 : A1;
        const unsigned short* B = s ? B2t : B1t;
        for (int k0 = 0; k0 < HID; k0 += BK) {
#pragma unroll
            for (int it = 0; it < 4; it++) {
                int row = lrow + it * 32;
                int r = r0 + row;
                uint4 va;
                if (r < N_NODES) va = *(const uint4*)&A[(size_t)r * HID + k0 + lseg * 8];
                else va = (uint4){0u, 0u, 0u, 0u};
                *(uint4*)&As[row * LPAD + lseg * 8] = va;
                uint4 vb = *(const uint4*)&B[(size_t)(c0 + row) * HID + k0 + lseg * 8];
                *(uint4*)&Bs[row * LPAD + lseg * 8] = vb;
            }
            __syncthreads();
#pragma unroll
            for (int kc = 0; kc < 2; kc++) {
                short8 a[4], b[4];
#pragma unroll
                for (int i = 0; i < 4; i++)
                    a[i] = *(const short8*)&As[(wm * 64 + i * 16 + l15) * LPAD + kc * 32 + quad * 8];
#pragma unroll
                for (int j = 0; j < 4; j++)
                    b[j] = *(const short8*)&Bs[(wn * 64 + j * 16 + l15) * LPAD + kc * 32 + quad * 8];
#pragma unroll
                for (int i = 0; i < 4; i++)
#pragma unroll
                    for (int j = 0; j < 4; j++)
                        acc[i][j] = __builtin_amdgcn_mfma_f32_16x16x32_bf16(a[i], b[j], acc[i][j], 0, 0, 0);
            }
            __syncthreads();
        }
    }

    float bv[4];
#pragma unroll
    for (int j = 0; j < 4; j++) bv[j] = bias[c0 + wn * 64 + j * 16 + l15];

#pragma unroll
    for (int i = 0; i < 4; i++) {
#pragma unroll
        for (int r = 0; r < 4; r++) {
            int m = r0 + wm * 64 + i * 16 + quad * 4 + r;
            if (m >= N_NODES) continue;
#pragma unroll
            for (int j = 0; j < 4; j++) {
                int n = c0 + wn * 64 + j * 16 + l15;
                float v = acc[i][j][r] + bv[j];
                if (F32OUT) ((float*)Cout)[(size_t)m * NCOL + n] = v;
                else ((unsigned short*)Cout)[(size_t)m * NCOL + n] = f2bf(v);
            }
        }
    }
}

extern "C" void kernel_launch(void* const* d_in, const int* in_sizes, int n_in,
                              void* d_out, int out_size, void* d_ws, size_t ws_size,
                              hipStream_t stream) {
    const float* x    = (const float*)d_in[0];
    const int*   ei   = (const int*)d_in[1];
    const float* w_in = (const float*)d_in[2];
    const float* b_in = (const float*)d_in[3];
    const float* g_in = (const float*)d_in[4];
    const float* be_in= (const float*)d_in[5];
    const float* wl1  = (const float*)d_in[6];
    const float* bl1  = (const float*)d_in[7];
    const float* wr1  = (const float*)d_in[8];
    const float* g1   = (const float*)d_in[9];
    const float* be1  = (const float*)d_in[10];
    const float* wl2  = (const float*)d_in[11];
    const float* bl2  = (const float*)d_in[12];
    const float* wr2  = (const float*)d_in[13];
    const float* g2   = (const float*)d_in[14];
    const float* be2  = (const float*)d_in[15];
    const float* wl3  = (const float*)d_in[16];
    const float* bl3  = (const float*)d_in[17];
    const float* wr3  = (const float*)d_in[18];
    float* out = (float*)d_out;

    char* p = (char*)d_ws;
    auto alloc = [&](size_t bytes) -> void* {
        void* r = (void*)p;
        p += (bytes + 255) & ~(size_t)255;
        return r;
    };
    unsigned short* bufA = (unsigned short*)alloc((size_t)N_NODES * HID * 2);
    unsigned short* bufB = (unsigned short*)alloc((size_t)N_NODES * HID * 2);
    unsigned short* agg  = (unsigned short*)alloc((size_t)N_NODES * HID * 2);
    unsigned short* wl1t = (unsigned short*)alloc((size_t)HID * HID * 2);
    unsigned short* wr1t = (unsigned short*)alloc((size_t)HID * HID * 2);
    unsigned short* wl2t = (unsigned short*)alloc((size_t)HID * HID * 2);
    unsigned short* wr2t = (unsigned short*)alloc((size_t)HID * HID * 2);
    unsigned short* wl3t = (unsigned short*)alloc((size_t)EMB * HID * 2);
    unsigned short* wr3t = (unsigned short*)alloc((size_t)EMB * HID * 2);
    int*   cnt        = (int*)alloc((size_t)N_NODES * 4);
    int*   row_off    = (int*)alloc((size_t)(N_NODES + 1) * 4);
    int*   fill_pos   = (int*)alloc((size_t)N_NODES * 4);
    int*   sorted_src = (int*)alloc((size_t)N_EDGES * 4);
    int*   part       = (int*)alloc((size_t)256 * 4);
    int*   partoff    = (int*)alloc((size_t)256 * 4);
    float* stats      = (float*)alloc((size_t)2 * HID * 4);
    float* ss         = (float*)alloc((size_t)2 * HID * 4);

    const int* e_src = ei;
    const int* e_dst = ei + N_EDGES;

    // CSR build (counting sort by dst) with parallel 3-phase scan
    hipMemsetAsync(cnt, 0, (size_t)N_NODES * 4, stream);
    k_count<<<(N_EDGES + 255) / 256, 256, 0, stream>>>(e_dst, cnt);
    k_reduce_cnt<<<N_SCAN_BLKS, 256, 0, stream>>>(cnt, part);
    k_scan_part<<<1, 256, 0, stream>>>(part, partoff, &row_off[N_NODES]);
    k_scan_final<<<N_SCAN_BLKS, 256, 0, stream>>>(cnt, partoff, row_off, fill_pos);
    k_scatter<<<(N_EDGES + 255) / 256, 256, 0, stream>>>(e_src, e_dst, fill_pos, sorted_src);

    // weights -> bf16 transposed
    k_wconv<<<HID, 256, 0, stream>>>(wl1, wl1t, HID);
    k_wconv<<<HID, 256, 0, stream>>>(wr1, wr1t, HID);
    k_wconv<<<HID, 256, 0, stream>>>(wl2, wl2t, HID);
    k_wconv<<<HID, 256, 0, stream>>>(wr2, wr2t, HID);
    k_wconv<<<EMB, 256, 0, stream>>>(wl3, wl3t, EMB);
    k_wconv<<<EMB, 256, 0, stream>>>(wr3, wr3t, EMB);

    auto bn = [&](unsigned short* h, const float* g, const float* b) {
        hipMemsetAsync(stats, 0, 2 * HID * 4, stream);
        k_bn_stats<<<1024, 128, 0, stream>>>(h, stats);
        k_bn_finalize<<<1, 256, 0, stream>>>(stats, g, b, ss);
        k_bn_apply_relu<<<(N_NODES * 32 + 255) / 256, 256, 0, stream>>>(h, ss);
    };

    // input projection + BN + ReLU
    k_input_proj<<<N_NODES, 256, 0, stream>>>(x, w_in, b_in, bufA);
    bn(bufA, g_in, be_in);

    dim3 gblock(256);
    dim3 grid2(2, (N_NODES + 127) / 128);
    dim3 grid1(1, (N_NODES + 127) / 128);
    int agg_blocks = (N_NODES * 32 + 255) / 256;

    // SAGE layer 1
    k_aggregate<<<agg_blocks, 256, 0, stream>>>(bufA, row_off, sorted_src, agg);
    k_gemm_mfma<HID, false><<<grid2, gblock, 0, stream>>>(agg, wl1t, bufA, wr1t, bl1, bufB);
    bn(bufB, g1, be1);

    // SAGE layer 2
    k_aggregate<<<agg_blocks, 256, 0, stream>>>(bufB, row_off, sorted_src, agg);
    k_gemm_mfma<HID, false><<<grid2, gblock, 0, stream>>>(agg, wl2t, bufB, wr2t, bl2, bufA);
    bn(bufA, g2, be2);

    // SAGE layer 3 (no BN/ReLU) -> fp32 d_out
    k_aggregate<<<agg_blocks, 256, 0, stream>>>(bufA, row_off, sorted_src, agg);
    k_gemm_mfma<EMB, true><<<grid1, gblock, 0, stream>>>(agg, wl3t, bufA, wr3t, bl3, out);
}

// Round 4
// 597.283 us; speedup vs baseline: 2.5007x; 1.2579x over previous
//
#include <hip/hip_runtime.h>

#define N_NODES 50000
#define N_EDGES 800000
#define IN_F 10
#define HID 256
#define EMB 128
#define BN_EPS 1e-5f
#define N_SCAN_BLKS ((N_NODES + 255) / 256)  // 196

typedef __attribute__((ext_vector_type(8))) short short8;
typedef __attribute__((ext_vector_type(4))) float floatx4;

__device__ __forceinline__ unsigned short f2bf(float f) {
    unsigned u = __float_as_uint(f);
    unsigned r = (u + 0x7fffu + ((u >> 16) & 1u)) >> 16;
    return (unsigned short)r;
}
__device__ __forceinline__ float bf_lo(unsigned int u) { return __uint_as_float(u << 16); }
__device__ __forceinline__ float bf_hi(unsigned int u) { return __uint_as_float(u & 0xffff0000u); }
__device__ __forceinline__ float bf2f(unsigned short s) { return __uint_as_float(((unsigned)s) << 16); }

// ---------------- CSR build ----------------
__global__ void k_count(const int* __restrict__ dst, int* __restrict__ cnt) {
    int e = blockIdx.x * 256 + threadIdx.x;
    if (e < N_EDGES) atomicAdd(&cnt[dst[e]], 1);
}

__global__ void k_reduce_cnt(const int* __restrict__ cnt, int* __restrict__ part) {
    __shared__ int sdata[256];
    int i = blockIdx.x * 256 + threadIdx.x;
    sdata[threadIdx.x] = (i < N_NODES) ? cnt[i] : 0;
    __syncthreads();
    for (int off = 128; off > 0; off >>= 1) {
        if (threadIdx.x < off) sdata[threadIdx.x] += sdata[threadIdx.x + off];
        __syncthreads();
    }
    if (threadIdx.x == 0) part[blockIdx.x] = sdata[0];
}

__global__ void k_scan_part(const int* __restrict__ part, int* __restrict__ partoff,
                            int* __restrict__ row_off_last) {
    __shared__ int buf[256];
    int tid = threadIdx.x;
    int v = (tid < N_SCAN_BLKS) ? part[tid] : 0;
    buf[tid] = v;
    __syncthreads();
    for (int off = 1; off < 256; off <<= 1) {
        int t = (tid >= off) ? buf[tid - off] : 0;
        __syncthreads();
        buf[tid] += t;
        __syncthreads();
    }
    if (tid < N_SCAN_BLKS) partoff[tid] = buf[tid] - v;
    if (tid == 255) *row_off_last = buf[255];
}

__global__ void k_scan_final(const int* __restrict__ cnt, const int* __restrict__ partoff,
                             int* __restrict__ row_off, int* __restrict__ fill_pos) {
    __shared__ int buf[256];
    int tid = threadIdx.x;
    int i = blockIdx.x * 256 + tid;
    int v = (i < N_NODES) ? cnt[i] : 0;
    buf[tid] = v;
    __syncthreads();
    for (int off = 1; off < 256; off <<= 1) {
        int t = (tid >= off) ? buf[tid - off] : 0;
        __syncthreads();
        buf[tid] += t;
        __syncthreads();
    }
    if (i < N_NODES) {
        int excl = partoff[blockIdx.x] + buf[tid] - v;
        row_off[i] = excl;
        fill_pos[i] = excl;
    }
}

__global__ void k_scatter(const int* __restrict__ src, const int* __restrict__ dst,
                          int* __restrict__ fill_pos, int* __restrict__ sorted_src) {
    int e = blockIdx.x * 256 + threadIdx.x;
    if (e < N_EDGES) {
        int d = dst[e];
        int p = atomicAdd(&fill_pos[d], 1);
        sorted_src[p] = src[e];
    }
}

// ---------------- all 6 weights convert+transpose in one kernel ----------------
__global__ void k_wconv_all(const float* __restrict__ wl1, const float* __restrict__ wr1,
                            const float* __restrict__ wl2, const float* __restrict__ wr2,
                            const float* __restrict__ wl3, const float* __restrict__ wr3,
                            unsigned short* __restrict__ wl1t, unsigned short* __restrict__ wr1t,
                            unsigned short* __restrict__ wl2t, unsigned short* __restrict__ wr2t,
                            unsigned short* __restrict__ wl3t, unsigned short* __restrict__ wr3t) {
    int idx = blockIdx.x * 256 + threadIdx.x;
    const int S = HID * HID;  // 65536
    if (idx < 4 * S) {
        int sel = idx >> 16;
        int o = idx & (S - 1);
        const float* w = sel == 0 ? wl1 : sel == 1 ? wr1 : sel == 2 ? wl2 : wr2;
        unsigned short* wt = sel == 0 ? wl1t : sel == 1 ? wr1t : sel == 2 ? wl2t : wr2t;
        int n = o >> 8, k = o & 255;
        wt[o] = f2bf(w[k * HID + n]);
    } else {
        int r = idx - 4 * S;  // [0, 2*32768)
        int sel = r >> 15;
        int o = r & 32767;
        const float* w = sel ? wr3 : wl3;
        unsigned short* wt = sel ? wr3t : wl3t;
        int n = o >> 8, k = o & 255;  // wt[n][k], n<128
        wt[o] = f2bf(w[k * EMB + n]);
    }
}

// ---------------- input projection + fused BN stats ----------------
__global__ void k_input_proj(const float* __restrict__ x, const float* __restrict__ w,
                             const float* __restrict__ bias, unsigned short* __restrict__ h,
                             float* __restrict__ stats) {
    int j = threadIdx.x;  // 256 columns
    float wj[IN_F];
#pragma unroll
    for (int k = 0; k < IN_F; k++) wj[k] = w[k * HID + j];
    float bj = bias[j];
    float s = 0.f, q = 0.f;
    for (int i = blockIdx.x; i < N_NODES; i += gridDim.x) {
        float acc = bj;
#pragma unroll
        for (int k = 0; k < IN_F; k++) acc += x[i * IN_F + k] * wj[k];
        h[(size_t)i * HID + j] = f2bf(acc);
        s += acc; q += acc * acc;
    }
    atomicAdd(&stats[j], s);
    atomicAdd(&stats[HID + j], q);
}

// ---------------- BN apply + ReLU (finalize folded in per-thread) ----------------
__global__ void k_bn_apply_relu(unsigned short* __restrict__ h, const float* __restrict__ stats,
                                const float* __restrict__ g, const float* __restrict__ b) {
    int idx = blockIdx.x * 256 + threadIdx.x;  // uint4 index over N_NODES*32
    if (idx >= N_NODES * 32) return;
    int q = idx & 31;
    int j0 = q * 8;
    const float invn = 1.0f / (float)N_NODES;
    float sc[8], sh[8];
#pragma unroll
    for (int k = 0; k < 8; k++) {
        float mu = stats[j0 + k] * invn;
        float var = stats[HID + j0 + k] * invn - mu * mu;
        float scale = g[j0 + k] * rsqrtf(var + BN_EPS);
        sc[k] = scale;
        sh[k] = b[j0 + k] - mu * scale;
    }
    uint4 v = ((uint4*)h)[idx];
    float f0 = fmaxf(bf_lo(v.x) * sc[0] + sh[0], 0.f);
    float f1 = fmaxf(bf_hi(v.x) * sc[1] + sh[1], 0.f);
    float f2 = fmaxf(bf_lo(v.y) * sc[2] + sh[2], 0.f);
    float f3 = fmaxf(bf_hi(v.y) * sc[3] + sh[3], 0.f);
    float f4 = fmaxf(bf_lo(v.z) * sc[4] + sh[4], 0.f);
    float f5 = fmaxf(bf_hi(v.z) * sc[5] + sh[5], 0.f);
    float f6 = fmaxf(bf_lo(v.w) * sc[6] + sh[6], 0.f);
    float f7 = fmaxf(bf_hi(v.w) * sc[7] + sh[7], 0.f);
    uint4 o;
    o.x = (unsigned)f2bf(f0) | ((unsigned)f2bf(f1) << 16);
    o.y = (unsigned)f2bf(f2) | ((unsigned)f2bf(f3) << 16);
    o.z = (unsigned)f2bf(f4) | ((unsigned)f2bf(f5) << 16);
    o.w = (unsigned)f2bf(f6) | ((unsigned)f2bf(f7) << 16);
    ((uint4*)h)[idx] = o;
}

// ---------------- neighbor mean aggregation: W uint4 lanes per node ----------------
template <int W>
__global__ void k_aggregate(const unsigned short* __restrict__ h, const int* __restrict__ row_off,
                            const int* __restrict__ sorted_src, unsigned short* __restrict__ agg) {
    int node = (blockIdx.x * blockDim.x + threadIdx.x) / W;
    int lane = threadIdx.x & (W - 1);
    if (node >= N_NODES) return;
    int beg = row_off[node], end = row_off[node + 1];
    const uint4* h4 = (const uint4*)h;
    float a0 = 0.f, a1 = 0.f, a2 = 0.f, a3 = 0.f, a4 = 0.f, a5 = 0.f, a6 = 0.f, a7 = 0.f;
    for (int e = beg; e < end; e++) {
        int s = sorted_src[e];
        uint4 v = h4[(size_t)s * W + lane];
        a0 += bf_lo(v.x); a1 += bf_hi(v.x);
        a2 += bf_lo(v.y); a3 += bf_hi(v.y);
        a4 += bf_lo(v.z); a5 += bf_hi(v.z);
        a6 += bf_lo(v.w); a7 += bf_hi(v.w);
    }
    int d = end - beg;
    float inv = 1.0f / (float)(d > 1 ? d : 1);
    uint4 o;
    o.x = (unsigned)f2bf(a0 * inv) | ((unsigned)f2bf(a1 * inv) << 16);
    o.y = (unsigned)f2bf(a2 * inv) | ((unsigned)f2bf(a3 * inv) << 16);
    o.z = (unsigned)f2bf(a4 * inv) | ((unsigned)f2bf(a5 * inv) << 16);
    o.w = (unsigned)f2bf(a6 * inv) | ((unsigned)f2bf(a7 * inv) << 16);
    ((uint4*)agg)[(size_t)node * W + lane] = o;
}

// ---------------- bf16 MFMA GEMM with optional dual product / stats / add-in ----------
#define BK 64
#define LPAD 72

template <int NCOL, bool F32OUT, bool STATS, bool ADDIN, bool HASBIAS, bool DUAL>
__global__ __launch_bounds__(256) void k_gemm_mfma(
        const unsigned short* __restrict__ A1, const unsigned short* __restrict__ B1t,
        const unsigned short* __restrict__ A2, const unsigned short* __restrict__ B2t,
        const float* __restrict__ bias, const unsigned short* __restrict__ addin,
        float* __restrict__ stats, void* __restrict__ Cout) {
    __shared__ unsigned short As[128 * LPAD];
    __shared__ unsigned short Bs[128 * LPAD];
    int t = threadIdx.x;
    int wave = t >> 6, lane = t & 63;
    int wm = wave >> 1, wn = wave & 1;
    int quad = lane >> 4, l15 = lane & 15;
    int r0 = blockIdx.y * 128, c0 = blockIdx.x * 128;

    floatx4 acc[4][4];
#pragma unroll
    for (int i = 0; i < 4; i++)
#pragma unroll
        for (int j = 0; j < 4; j++) acc[i][j] = (floatx4){0.f, 0.f, 0.f, 0.f};

    int lrow = t >> 3;
    int lseg = t & 7;

#pragma unroll
    for (int s = 0; s < (DUAL ? 2 : 1); s++) {
        const unsigned short* A = (DUAL && s) ? A2 : A1;
        const unsigned short* B = (DUAL && s) ? B2t : B1t;
        for (int k0 = 0; k0 < HID; k0 += BK) {
#pragma unroll
            for (int it = 0; it < 4; it++) {
                int row = lrow + it * 32;
                int r = r0 + row;
                uint4 va;
                if (r < N_NODES) va = *(const uint4*)&A[(size_t)r * HID + k0 + lseg * 8];
                else va = (uint4){0u, 0u, 0u, 0u};
                *(uint4*)&As[row * LPAD + lseg * 8] = va;
                uint4 vb = *(const uint4*)&B[(size_t)(c0 + row) * HID + k0 + lseg * 8];
                *(uint4*)&Bs[row * LPAD + lseg * 8] = vb;
            }
            __syncthreads();
#pragma unroll
            for (int kc = 0; kc < 2; kc++) {
                short8 a[4], b[4];
#pragma unroll
                for (int i = 0; i < 4; i++)
                    a[i] = *(const short8*)&As[(wm * 64 + i * 16 + l15) * LPAD + kc * 32 + quad * 8];
#pragma unroll
                for (int j = 0; j < 4; j++)
                    b[j] = *(const short8*)&Bs[(wn * 64 + j * 16 + l15) * LPAD + kc * 32 + quad * 8];
#pragma unroll
                for (int i = 0; i < 4; i++)
#pragma unroll
                    for (int j = 0; j < 4; j++)
                        acc[i][j] = __builtin_amdgcn_mfma_f32_16x16x32_bf16(a[i], b[j], acc[i][j], 0, 0, 0);
            }
            __syncthreads();
        }
    }

    float bv[4];
#pragma unroll
    for (int j = 0; j < 4; j++) bv[j] = HASBIAS ? bias[c0 + wn * 64 + j * 16 + l15] : 0.f;

    float s_part[4] = {0.f, 0.f, 0.f, 0.f};
    float q_part[4] = {0.f, 0.f, 0.f, 0.f};

#pragma unroll
    for (int i = 0; i < 4; i++) {
#pragma unroll
        for (int r = 0; r < 4; r++) {
            int m = r0 + wm * 64 + i * 16 + quad * 4 + r;
            if (m >= N_NODES) continue;
#pragma unroll
            for (int j = 0; j < 4; j++) {
                int n = c0 + wn * 64 + j * 16 + l15;
                float v = acc[i][j][r] + bv[j];
                if (ADDIN) v += bf2f(addin[(size_t)m * NCOL + n]);
                if (STATS) { s_part[j] += v; q_part[j] += v * v; }
                if (F32OUT) ((float*)Cout)[(size_t)m * NCOL + n] = v;
                else ((unsigned short*)Cout)[(size_t)m * NCOL + n] = f2bf(v);
            }
        }
    }

    if (STATS) {
        float* sred = (float*)As;  // safe: all LDS reads completed before last barrier
        sred[t] = 0.f;             // 256 floats: [0,128)=sum, [128,256)=sumsq
        __syncthreads();
#pragma unroll
        for (int j = 0; j < 4; j++) {
            int cl = wn * 64 + j * 16 + l15;
            atomicAdd(&sred[cl], s_part[j]);
            atomicAdd(&sred[128 + cl], q_part[j]);
        }
        __syncthreads();
        if (t < 128) {
            atomicAdd(&stats[c0 + t], sred[t]);
            atomicAdd(&stats[HID + c0 + t], sred[128 + t]);
        }
    }
}

extern "C" void kernel_launch(void* const* d_in, const int* in_sizes, int n_in,
                              void* d_out, int out_size, void* d_ws, size_t ws_size,
                              hipStream_t stream) {
    const float* x    = (const float*)d_in[0];
    const int*   ei   = (const int*)d_in[1];
    const float* w_in = (const float*)d_in[2];
    const float* b_in = (const float*)d_in[3];
    const float* g_in = (const float*)d_in[4];
    const float* be_in= (const float*)d_in[5];
    const float* wl1  = (const float*)d_in[6];
    const float* bl1  = (const float*)d_in[7];
    const float* wr1  = (const float*)d_in[8];
    const float* g1   = (const float*)d_in[9];
    const float* be1  = (const float*)d_in[10];
    const float* wl2  = (const float*)d_in[11];
    const float* bl2  = (const float*)d_in[12];
    const float* wr2  = (const float*)d_in[13];
    const float* g2   = (const float*)d_in[14];
    const float* be2  = (const float*)d_in[15];
    const float* wl3  = (const float*)d_in[16];
    const float* bl3  = (const float*)d_in[17];
    const float* wr3  = (const float*)d_in[18];
    float* out = (float*)d_out;

    char* p = (char*)d_ws;
    auto alloc = [&](size_t bytes) -> void* {
        void* r = (void*)p;
        p += (bytes + 255) & ~(size_t)255;
        return r;
    };
    // zero-region: cnt + 3 stats buffers, contiguous
    int*   cnt    = (int*)alloc((size_t)N_NODES * 4);
    float* stats0 = (float*)alloc((size_t)2 * HID * 4);
    float* stats1 = (float*)alloc((size_t)2 * HID * 4);
    float* stats2 = (float*)alloc((size_t)2 * HID * 4);
    size_t zlen = (size_t)((char*)stats2 + 2 * HID * 4 - (char*)cnt);

    unsigned short* bufA = (unsigned short*)alloc((size_t)N_NODES * HID * 2);
    unsigned short* bufB = (unsigned short*)alloc((size_t)N_NODES * HID * 2);
    unsigned short* bufC = (unsigned short*)alloc((size_t)N_NODES * HID * 2);
    unsigned short* wl1t = (unsigned short*)alloc((size_t)HID * HID * 2);
    unsigned short* wr1t = (unsigned short*)alloc((size_t)HID * HID * 2);
    unsigned short* wl2t = (unsigned short*)alloc((size_t)HID * HID * 2);
    unsigned short* wr2t = (unsigned short*)alloc((size_t)HID * HID * 2);
    unsigned short* wl3t = (unsigned short*)alloc((size_t)EMB * HID * 2);
    unsigned short* wr3t = (unsigned short*)alloc((size_t)EMB * HID * 2);
    int*   row_off    = (int*)alloc((size_t)(N_NODES + 1) * 4);
    int*   fill_pos   = (int*)alloc((size_t)N_NODES * 4);
    int*   sorted_src = (int*)alloc((size_t)N_EDGES * 4);
    int*   part       = (int*)alloc((size_t)256 * 4);
    int*   partoff    = (int*)alloc((size_t)256 * 4);

    const int* e_src = ei;
    const int* e_dst = ei + N_EDGES;

    hipMemsetAsync(cnt, 0, zlen, stream);

    // CSR build
    k_count<<<(N_EDGES + 255) / 256, 256, 0, stream>>>(e_dst, cnt);
    k_reduce_cnt<<<N_SCAN_BLKS, 256, 0, stream>>>(cnt, part);
    k_scan_part<<<1, 256, 0, stream>>>(part, partoff, &row_off[N_NODES]);
    k_scan_final<<<N_SCAN_BLKS, 256, 0, stream>>>(cnt, partoff, row_off, fill_pos);
    k_scatter<<<(N_EDGES + 255) / 256, 256, 0, stream>>>(e_src, e_dst, fill_pos, sorted_src);

    // weights
    k_wconv_all<<<(4 * HID * HID + 2 * EMB * HID) / 256, 256, 0, stream>>>(
        wl1, wr1, wl2, wr2, wl3, wr3, wl1t, wr1t, wl2t, wr2t, wl3t, wr3t);

    // input projection (+stats0), BN apply
    k_input_proj<<<256, 256, 0, stream>>>(x, w_in, b_in, bufA, stats0);
    k_bn_apply_relu<<<(N_NODES * 32 + 255) / 256, 256, 0, stream>>>(bufA, stats0, g_in, be_in);

    dim3 gblock(256);
    dim3 grid2(2, (N_NODES + 127) / 128);  // N=256
    dim3 grid1(1, (N_NODES + 127) / 128);  // N=128
    int aggW32_blocks = (N_NODES * 32 + 255) / 256;
    int aggW16_blocks = (N_NODES * 16 + 255) / 256;

    // SAGE layer 1: h1 = agg@wl1 + bl1 + h0@wr1 (+stats1)
    k_aggregate<32><<<aggW32_blocks, 256, 0, stream>>>(bufA, row_off, sorted_src, bufC);
    k_gemm_mfma<HID, false, true, false, true, true><<<grid2, gblock, 0, stream>>>(
        bufC, wl1t, bufA, wr1t, bl1, nullptr, stats1, bufB);
    k_bn_apply_relu<<<(N_NODES * 32 + 255) / 256, 256, 0, stream>>>(bufB, stats1, g1, be1);

    // SAGE layer 2: h2 = agg@wl2 + bl2 + h1@wr2 (+stats2)
    k_aggregate<32><<<aggW32_blocks, 256, 0, stream>>>(bufB, row_off, sorted_src, bufC);
    k_gemm_mfma<HID, false, true, false, true, true><<<grid2, gblock, 0, stream>>>(
        bufC, wl2t, bufB, wr2t, bl2, nullptr, stats2, bufA);
    k_bn_apply_relu<<<(N_NODES * 32 + 255) / 256, 256, 0, stream>>>(bufA, stats2, g2, be2);

    // SAGE layer 3 (reordered): g3 = h2@wl3 ; agg128 = D^-1 A g3 ; out = agg128 + h2@wr3 + bl3
    k_gemm_mfma<EMB, false, false, false, false, false><<<grid1, gblock, 0, stream>>>(
        bufA, wl3t, nullptr, nullptr, nullptr, nullptr, nullptr, bufB);
    k_aggregate<16><<<aggW16_blocks, 256, 0, stream>>>(bufB, row_off, sorted_src, bufC);
    k_gemm_mfma<EMB, true, false, true, true, false><<<grid1, gblock, 0, stream>>>(
        bufA, wr3t, nullptr, nullptr, bl3, bufC, nullptr, out);
}

// Round 5
// 570.163 us; speedup vs baseline: 2.6196x; 1.0476x over previous
//
#include <hip/hip_runtime.h>

#define N_NODES 50000
#define N_EDGES 800000
#define IN_F 10
#define HID 256
#define EMB 128
#define BN_EPS 1e-5f
#define N_SCAN_BLKS ((N_NODES + 255) / 256)  // 196

typedef __attribute__((ext_vector_type(8))) short short8;
typedef __attribute__((ext_vector_type(4))) float floatx4;

__device__ __forceinline__ unsigned short f2bf(float f) {
    unsigned u = __float_as_uint(f);
    unsigned r = (u + 0x7fffu + ((u >> 16) & 1u)) >> 16;
    return (unsigned short)r;
}
__device__ __forceinline__ float bf_lo(unsigned int u) { return __uint_as_float(u << 16); }
__device__ __forceinline__ float bf_hi(unsigned int u) { return __uint_as_float(u & 0xffff0000u); }
__device__ __forceinline__ float bf2f(unsigned short s) { return __uint_as_float(((unsigned)s) << 16); }

// ---------------- CSR build ----------------
__global__ void k_count(const int* __restrict__ dst, int* __restrict__ cnt) {
    int e = blockIdx.x * 256 + threadIdx.x;
    if (e < N_EDGES) atomicAdd(&cnt[dst[e]], 1);
}

__global__ void k_reduce_cnt(const int* __restrict__ cnt, int* __restrict__ part) {
    __shared__ int sdata[256];
    int i = blockIdx.x * 256 + threadIdx.x;
    sdata[threadIdx.x] = (i < N_NODES) ? cnt[i] : 0;
    __syncthreads();
    for (int off = 128; off > 0; off >>= 1) {
        if (threadIdx.x < off) sdata[threadIdx.x] += sdata[threadIdx.x + off];
        __syncthreads();
    }
    if (threadIdx.x == 0) part[blockIdx.x] = sdata[0];
}

__global__ void k_scan_part(const int* __restrict__ part, int* __restrict__ partoff,
                            int* __restrict__ row_off_last) {
    __shared__ int buf[256];
    int tid = threadIdx.x;
    int v = (tid < N_SCAN_BLKS) ? part[tid] : 0;
    buf[tid] = v;
    __syncthreads();
    for (int off = 1; off < 256; off <<= 1) {
        int t = (tid >= off) ? buf[tid - off] : 0;
        __syncthreads();
        buf[tid] += t;
        __syncthreads();
    }
    if (tid < N_SCAN_BLKS) partoff[tid] = buf[tid] - v;
    if (tid == 255) *row_off_last = buf[255];
}

__global__ void k_scan_final(const int* __restrict__ cnt, const int* __restrict__ partoff,
                             int* __restrict__ row_off, int* __restrict__ fill_pos) {
    __shared__ int buf[256];
    int tid = threadIdx.x;
    int i = blockIdx.x * 256 + tid;
    int v = (i < N_NODES) ? cnt[i] : 0;
    buf[tid] = v;
    __syncthreads();
    for (int off = 1; off < 256; off <<= 1) {
        int t = (tid >= off) ? buf[tid - off] : 0;
        __syncthreads();
        buf[tid] += t;
        __syncthreads();
    }
    if (i < N_NODES) {
        int excl = partoff[blockIdx.x] + buf[tid] - v;
        row_off[i] = excl;
        fill_pos[i] = excl;
    }
}

__global__ void k_scatter(const int* __restrict__ src, const int* __restrict__ dst,
                          int* __restrict__ fill_pos, int* __restrict__ sorted_src) {
    int e = blockIdx.x * 256 + threadIdx.x;
    if (e < N_EDGES) {
        int d = dst[e];
        int p = atomicAdd(&fill_pos[d], 1);
        sorted_src[p] = src[e];
    }
}

// ---------------- all 6 weights convert+transpose in one kernel ----------------
__global__ void k_wconv_all(const float* __restrict__ wl1, const float* __restrict__ wr1,
                            const float* __restrict__ wl2, const float* __restrict__ wr2,
                            const float* __restrict__ wl3, const float* __restrict__ wr3,
                            unsigned short* __restrict__ wl1t, unsigned short* __restrict__ wr1t,
                            unsigned short* __restrict__ wl2t, unsigned short* __restrict__ wr2t,
                            unsigned short* __restrict__ wl3t, unsigned short* __restrict__ wr3t) {
    int idx = blockIdx.x * 256 + threadIdx.x;
    const int S = HID * HID;  // 65536
    if (idx < 4 * S) {
        int sel = idx >> 16;
        int o = idx & (S - 1);
        const float* w = sel == 0 ? wl1 : sel == 1 ? wr1 : sel == 2 ? wl2 : wr2;
        unsigned short* wt = sel == 0 ? wl1t : sel == 1 ? wr1t : sel == 2 ? wl2t : wr2t;
        int n = o >> 8, k = o & 255;
        wt[o] = f2bf(w[k * HID + n]);
    } else {
        int r = idx - 4 * S;  // [0, 2*32768)
        int sel = r >> 15;
        int o = r & 32767;
        const float* w = sel ? wr3 : wl3;
        unsigned short* wt = sel ? wr3t : wl3t;
        int n = o >> 8, k = o & 255;  // wt[n][k], n<128
        wt[o] = f2bf(w[k * EMB + n]);
    }
}

// ---------------- input projection + fused BN stats (v2: 32 thr/node, uint4 stores) ------
// 1024 blocks x 256 threads; block-iteration covers 8 nodes x 32 col-groups.
#define IP_BLOCKS 1024
__global__ __launch_bounds__(256) void k_input_proj(
        const float* __restrict__ x, const float* __restrict__ w,
        const float* __restrict__ bias, unsigned short* __restrict__ h,
        float* __restrict__ stats) {
    __shared__ float sbuf[2048];
    __shared__ float qbuf[2048];
    int t = threadIdx.x;
    int jg = t & 31;        // col group: cols jg*8 .. jg*8+7
    int ns = t >> 5;        // node slot 0..7
    int j0 = jg * 8;

    float wreg[IN_F][8];
#pragma unroll
    for (int k = 0; k < IN_F; k++)
#pragma unroll
        for (int c = 0; c < 8; c++) wreg[k][c] = w[k * HID + j0 + c];
    float bj[8];
#pragma unroll
    for (int c = 0; c < 8; c++) bj[c] = bias[j0 + c];

    float s[8] = {}, q[8] = {};
    const int stride = IP_BLOCKS * 8;
    for (int base = blockIdx.x * 8 + ns; base < N_NODES; base += stride) {
        float xr[IN_F];
#pragma unroll
        for (int k = 0; k < IN_F; k++) xr[k] = x[base * IN_F + k];
        float acc[8];
#pragma unroll
        for (int c = 0; c < 8; c++) {
            float a = bj[c];
#pragma unroll
            for (int k = 0; k < IN_F; k++) a += xr[k] * wreg[k][c];
            acc[c] = a;
            s[c] += a;
            q[c] += a * a;
        }
        uint4 o;
        o.x = (unsigned)f2bf(acc[0]) | ((unsigned)f2bf(acc[1]) << 16);
        o.y = (unsigned)f2bf(acc[2]) | ((unsigned)f2bf(acc[3]) << 16);
        o.z = (unsigned)f2bf(acc[4]) | ((unsigned)f2bf(acc[5]) << 16);
        o.w = (unsigned)f2bf(acc[6]) | ((unsigned)f2bf(acc[7]) << 16);
        ((uint4*)h)[(size_t)base * 32 + jg] = o;
    }

#pragma unroll
    for (int c = 0; c < 8; c++) {
        sbuf[ns * 256 + j0 + c] = s[c];
        qbuf[ns * 256 + j0 + c] = q[c];
    }
    __syncthreads();
    // t indexes the 256 columns
    float ss = 0.f, qq = 0.f;
#pragma unroll
    for (int n2 = 0; n2 < 8; n2++) {
        ss += sbuf[n2 * 256 + t];
        qq += qbuf[n2 * 256 + t];
    }
    atomicAdd(&stats[t], ss);
    atomicAdd(&stats[HID + t], qq);
}

// ---------------- BN apply + ReLU (finalize folded in per-thread) ----------------
__global__ void k_bn_apply_relu(unsigned short* __restrict__ h, const float* __restrict__ stats,
                                const float* __restrict__ g, const float* __restrict__ b) {
    int idx = blockIdx.x * 256 + threadIdx.x;  // uint4 index over N_NODES*32
    if (idx >= N_NODES * 32) return;
    int q = idx & 31;
    int j0 = q * 8;
    const float invn = 1.0f / (float)N_NODES;
    float sc[8], sh[8];
#pragma unroll
    for (int k = 0; k < 8; k++) {
        float mu = stats[j0 + k] * invn;
        float var = stats[HID + j0 + k] * invn - mu * mu;
        float scale = g[j0 + k] * rsqrtf(var + BN_EPS);
        sc[k] = scale;
        sh[k] = b[j0 + k] - mu * scale;
    }
    uint4 v = ((uint4*)h)[idx];
    float f0 = fmaxf(bf_lo(v.x) * sc[0] + sh[0], 0.f);
    float f1 = fmaxf(bf_hi(v.x) * sc[1] + sh[1], 0.f);
    float f2 = fmaxf(bf_lo(v.y) * sc[2] + sh[2], 0.f);
    float f3 = fmaxf(bf_hi(v.y) * sc[3] + sh[3], 0.f);
    float f4 = fmaxf(bf_lo(v.z) * sc[4] + sh[4], 0.f);
    float f5 = fmaxf(bf_hi(v.z) * sc[5] + sh[5], 0.f);
    float f6 = fmaxf(bf_lo(v.w) * sc[6] + sh[6], 0.f);
    float f7 = fmaxf(bf_hi(v.w) * sc[7] + sh[7], 0.f);
    uint4 o;
    o.x = (unsigned)f2bf(f0) | ((unsigned)f2bf(f1) << 16);
    o.y = (unsigned)f2bf(f2) | ((unsigned)f2bf(f3) << 16);
    o.z = (unsigned)f2bf(f4) | ((unsigned)f2bf(f5) << 16);
    o.w = (unsigned)f2bf(f6) | ((unsigned)f2bf(f7) << 16);
    ((uint4*)h)[idx] = o;
}

// ---------------- neighbor mean aggregation: W uint4 lanes per node ----------------
template <int W>
__global__ void k_aggregate(const unsigned short* __restrict__ h, const int* __restrict__ row_off,
                            const int* __restrict__ sorted_src, unsigned short* __restrict__ agg) {
    int node = (blockIdx.x * blockDim.x + threadIdx.x) / W;
    int lane = threadIdx.x & (W - 1);
    if (node >= N_NODES) return;
    int beg = row_off[node], end = row_off[node + 1];
    const uint4* h4 = (const uint4*)h;
    float a0 = 0.f, a1 = 0.f, a2 = 0.f, a3 = 0.f, a4 = 0.f, a5 = 0.f, a6 = 0.f, a7 = 0.f;
    for (int e = beg; e < end; e++) {
        int s = sorted_src[e];
        uint4 v = h4[(size_t)s * W + lane];
        a0 += bf_lo(v.x); a1 += bf_hi(v.x);
        a2 += bf_lo(v.y); a3 += bf_hi(v.y);
        a4 += bf_lo(v.z); a5 += bf_hi(v.z);
        a6 += bf_lo(v.w); a7 += bf_hi(v.w);
    }
    int d = end - beg;
    float inv = 1.0f / (float)(d > 1 ? d : 1);
    uint4 o;
    o.x = (unsigned)f2bf(a0 * inv) | ((unsigned)f2bf(a1 * inv) << 16);
    o.y = (unsigned)f2bf(a2 * inv) | ((unsigned)f2bf(a3 * inv) << 16);
    o.z = (unsigned)f2bf(a4 * inv) | ((unsigned)f2bf(a5 * inv) << 16);
    o.w = (unsigned)f2bf(a6 * inv) | ((unsigned)f2bf(a7 * inv) << 16);
    ((uint4*)agg)[(size_t)node * W + lane] = o;
}

// ---------------- bf16 MFMA GEMM with optional dual product / stats / add-in ----------
#define BK 64
#define LPAD 72

template <int NCOL, bool F32OUT, bool STATS, bool ADDIN, bool HASBIAS, bool DUAL>
__global__ __launch_bounds__(256) void k_gemm_mfma(
        const unsigned short* __restrict__ A1, const unsigned short* __restrict__ B1t,
        const unsigned short* __restrict__ A2, const unsigned short* __restrict__ B2t,
        const float* __restrict__ bias, const unsigned short* __restrict__ addin,
        float* __restrict__ stats, void* __restrict__ Cout) {
    __shared__ unsigned short As[128 * LPAD];
    __shared__ unsigned short Bs[128 * LPAD];
    int t = threadIdx.x;
    int wave = t >> 6, lane = t & 63;
    int wm = wave >> 1, wn = wave & 1;
    int quad = lane >> 4, l15 = lane & 15;
    int r0 = blockIdx.y * 128, c0 = blockIdx.x * 128;

    floatx4 acc[4][4];
#pragma unroll
    for (int i = 0; i < 4; i++)
#pragma unroll
        for (int j = 0; j < 4; j++) acc[i][j] = (floatx4){0.f, 0.f, 0.f, 0.f};

    int lrow = t >> 3;
    int lseg = t & 7;

#pragma unroll
    for (int s = 0; s < (DUAL ? 2 : 1); s++) {
        const unsigned short* A = (DUAL && s) ? A2 : A1;
        const unsigned short* B = (DUAL && s) ? B2t : B1t;
        for (int k0 = 0; k0 < HID; k0 += BK) {
#pragma unroll
            for (int it = 0; it < 4; it++) {
                int row = lrow + it * 32;
                int r = r0 + row;
                uint4 va;
                if (r < N_NODES) va = *(const uint4*)&A[(size_t)r * HID + k0 + lseg * 8];
                else va = (uint4){0u, 0u, 0u, 0u};
                *(uint4*)&As[row * LPAD + lseg * 8] = va;
                uint4 vb = *(const uint4*)&B[(size_t)(c0 + row) * HID + k0 + lseg * 8];
                *(uint4*)&Bs[row * LPAD + lseg * 8] = vb;
            }
            __syncthreads();
#pragma unroll
            for (int kc = 0; kc < 2; kc++) {
                short8 a[4], b[4];
#pragma unroll
                for (int i = 0; i < 4; i++)
                    a[i] = *(const short8*)&As[(wm * 64 + i * 16 + l15) * LPAD + kc * 32 + quad * 8];
#pragma unroll
                for (int j = 0; j < 4; j++)
                    b[j] = *(const short8*)&Bs[(wn * 64 + j * 16 + l15) * LPAD + kc * 32 + quad * 8];
#pragma unroll
                for (int i = 0; i < 4; i++)
#pragma unroll
                    for (int j = 0; j < 4; j++)
                        acc[i][j] = __builtin_amdgcn_mfma_f32_16x16x32_bf16(a[i], b[j], acc[i][j], 0, 0, 0);
            }
            __syncthreads();
        }
    }

    float bv[4];
#pragma unroll
    for (int j = 0; j < 4; j++) bv[j] = HASBIAS ? bias[c0 + wn * 64 + j * 16 + l15] : 0.f;

    float s_part[4] = {0.f, 0.f, 0.f, 0.f};
    float q_part[4] = {0.f, 0.f, 0.f, 0.f};

#pragma unroll
    for (int i = 0; i < 4; i++) {
#pragma unroll
        for (int r = 0; r < 4; r++) {
            int m = r0 + wm * 64 + i * 16 + quad * 4 + r;
            if (m >= N_NODES) continue;
#pragma unroll
            for (int j = 0; j < 4; j++) {
                int n = c0 + wn * 64 + j * 16 + l15;
                float v = acc[i][j][r] + bv[j];
                if (ADDIN) v += bf2f(addin[(size_t)m * NCOL + n]);
                if (STATS) { s_part[j] += v; q_part[j] += v * v; }
                if (F32OUT) ((float*)Cout)[(size_t)m * NCOL + n] = v;
                else ((unsigned short*)Cout)[(size_t)m * NCOL + n] = f2bf(v);
            }
        }
    }

    if (STATS) {
        float* sred = (float*)As;  // safe: all LDS reads completed before last barrier
        sred[t] = 0.f;             // 256 floats: [0,128)=sum, [128,256)=sumsq
        __syncthreads();
#pragma unroll
        for (int j = 0; j < 4; j++) {
            int cl = wn * 64 + j * 16 + l15;
            atomicAdd(&sred[cl], s_part[j]);
            atomicAdd(&sred[128 + cl], q_part[j]);
        }
        __syncthreads();
        if (t < 128) {
            atomicAdd(&stats[c0 + t], sred[t]);
            atomicAdd(&stats[HID + c0 + t], sred[128 + t]);
        }
    }
}

extern "C" void kernel_launch(void* const* d_in, const int* in_sizes, int n_in,
                              void* d_out, int out_size, void* d_ws, size_t ws_size,
                              hipStream_t stream) {
    const float* x    = (const float*)d_in[0];
    const int*   ei   = (const int*)d_in[1];
    const float* w_in = (const float*)d_in[2];
    const float* b_in = (const float*)d_in[3];
    const float* g_in = (const float*)d_in[4];
    const float* be_in= (const float*)d_in[5];
    const float* wl1  = (const float*)d_in[6];
    const float* bl1  = (const float*)d_in[7];
    const float* wr1  = (const float*)d_in[8];
    const float* g1   = (const float*)d_in[9];
    const float* be1  = (const float*)d_in[10];
    const float* wl2  = (const float*)d_in[11];
    const float* bl2  = (const float*)d_in[12];
    const float* wr2  = (const float*)d_in[13];
    const float* g2   = (const float*)d_in[14];
    const float* be2  = (const float*)d_in[15];
    const float* wl3  = (const float*)d_in[16];
    const float* bl3  = (const float*)d_in[17];
    const float* wr3  = (const float*)d_in[18];
    float* out = (float*)d_out;

    char* p = (char*)d_ws;
    auto alloc = [&](size_t bytes) -> void* {
        void* r = (void*)p;
        p += (bytes + 255) & ~(size_t)255;
        return r;
    };
    // zero-region: cnt + 3 stats buffers, contiguous
    int*   cnt    = (int*)alloc((size_t)N_NODES * 4);
    float* stats0 = (float*)alloc((size_t)2 * HID * 4);
    float* stats1 = (float*)alloc((size_t)2 * HID * 4);
    float* stats2 = (float*)alloc((size_t)2 * HID * 4);
    size_t zlen = (size_t)((char*)stats2 + 2 * HID * 4 - (char*)cnt);

    unsigned short* bufA = (unsigned short*)alloc((size_t)N_NODES * HID * 2);
    unsigned short* bufB = (unsigned short*)alloc((size_t)N_NODES * HID * 2);
    unsigned short* bufC = (unsigned short*)alloc((size_t)N_NODES * HID * 2);
    unsigned short* wl1t = (unsigned short*)alloc((size_t)HID * HID * 2);
    unsigned short* wr1t = (unsigned short*)alloc((size_t)HID * HID * 2);
    unsigned short* wl2t = (unsigned short*)alloc((size_t)HID * HID * 2);
    unsigned short* wr2t = (unsigned short*)alloc((size_t)HID * HID * 2);
    unsigned short* wl3t = (unsigned short*)alloc((size_t)EMB * HID * 2);
    unsigned short* wr3t = (unsigned short*)alloc((size_t)EMB * HID * 2);
    int*   row_off    = (int*)alloc((size_t)(N_NODES + 1) * 4);
    int*   fill_pos   = (int*)alloc((size_t)N_NODES * 4);
    int*   sorted_src = (int*)alloc((size_t)N_EDGES * 4);
    int*   part       = (int*)alloc((size_t)256 * 4);
    int*   partoff    = (int*)alloc((size_t)256 * 4);

    const int* e_src = ei;
    const int* e_dst = ei + N_EDGES;

    hipMemsetAsync(cnt, 0, zlen, stream);

    // CSR build
    k_count<<<(N_EDGES + 255) / 256, 256, 0, stream>>>(e_dst, cnt);
    k_reduce_cnt<<<N_SCAN_BLKS, 256, 0, stream>>>(cnt, part);
    k_scan_part<<<1, 256, 0, stream>>>(part, partoff, &row_off[N_NODES]);
    k_scan_final<<<N_SCAN_BLKS, 256, 0, stream>>>(cnt, partoff, row_off, fill_pos);
    k_scatter<<<(N_EDGES + 255) / 256, 256, 0, stream>>>(e_src, e_dst, fill_pos, sorted_src);

    // weights
    k_wconv_all<<<(4 * HID * HID + 2 * EMB * HID) / 256, 256, 0, stream>>>(
        wl1, wr1, wl2, wr2, wl3, wr3, wl1t, wr1t, wl2t, wr2t, wl3t, wr3t);

    // input projection (+stats0), BN apply
    k_input_proj<<<IP_BLOCKS, 256, 0, stream>>>(x, w_in, b_in, bufA, stats0);
    k_bn_apply_relu<<<(N_NODES * 32 + 255) / 256, 256, 0, stream>>>(bufA, stats0, g_in, be_in);

    dim3 gblock(256);
    dim3 grid2(2, (N_NODES + 127) / 128);  // N=256
    dim3 grid1(1, (N_NODES + 127) / 128);  // N=128
    int aggW32_blocks = (N_NODES * 32 + 255) / 256;
    int aggW16_blocks = (N_NODES * 16 + 255) / 256;

    // SAGE layer 1: h1 = agg@wl1 + bl1 + h0@wr1 (+stats1)
    k_aggregate<32><<<aggW32_blocks, 256, 0, stream>>>(bufA, row_off, sorted_src, bufC);
    k_gemm_mfma<HID, false, true, false, true, true><<<grid2, gblock, 0, stream>>>(
        bufC, wl1t, bufA, wr1t, bl1, nullptr, stats1, bufB);
    k_bn_apply_relu<<<(N_NODES * 32 + 255) / 256, 256, 0, stream>>>(bufB, stats1, g1, be1);

    // SAGE layer 2: h2 = agg@wl2 + bl2 + h1@wr2 (+stats2)
    k_aggregate<32><<<aggW32_blocks, 256, 0, stream>>>(bufB, row_off, sorted_src, bufC);
    k_gemm_mfma<HID, false, true, false, true, true><<<grid2, gblock, 0, stream>>>(
        bufC, wl2t, bufB, wr2t, bl2, nullptr, stats2, bufA);
    k_bn_apply_relu<<<(N_NODES * 32 + 255) / 256, 256, 0, stream>>>(bufA, stats2, g2, be2);

    // SAGE layer 3 (reordered): g3 = h2@wl3 ; agg128 = D^-1 A g3 ; out = agg128 + h2@wr3 + bl3
    k_gemm_mfma<EMB, false, false, false, false, false><<<grid1, gblock, 0, stream>>>(
        bufA, wl3t, nullptr, nullptr, nullptr, nullptr, nullptr, bufB);
    k_aggregate<16><<<aggW16_blocks, 256, 0, stream>>>(bufB, row_off, sorted_src, bufC);
    k_gemm_mfma<EMB, true, false, true, true, false><<<grid1, gblock, 0, stream>>>(
        bufA, wr3t, nullptr, nullptr, bl3, bufC, nullptr, out);
}